// Round 1
// baseline (1071.505 us; speedup 1.0000x reference)
//
#include <hip/hip_runtime.h>
#include <hip/hip_bf16.h>
#include <math.h>

// Problem constants (from reference)
#define BB 2
#define SS 2048
#define DM 1024
#define HH 16
#define DK 64
#define PADW 68   // LDS row pad: 68 floats = 272B, 16B-aligned rows, breaks bank conflicts

// ---------------------------------------------------------------------------
// proj_kernel: out[b,h,s,k] = X[b,s,:] @ W[h,:,k] + bias[h,k]
// 64x64 output tile per block, 256 threads, 4x4 micro-tile per thread.
// LDS: Xs transposed [kk][row], Ws natural [kk][col] -> inner loop is
// 2x ds_read_b128 + 16 fmaf per kk.
// ---------------------------------------------------------------------------
__global__ __launch_bounds__(256) void proj_kernel(
    const float* __restrict__ X,    // [B,S,DM]
    const float* __restrict__ W,    // [H,DM,DK]
    const float* __restrict__ bias, // [H,DK]
    float* __restrict__ out)        // [B,H,S,DK]
{
    __shared__ float Xs[64][PADW];
    __shared__ float Ws[64][PADW];
    const int tid = threadIdx.x;
    const int tx = tid & 15, ty = tid >> 4;
    const int b = blockIdx.y / HH, h = blockIdx.y % HH;
    const int row0 = blockIdx.x * 64;
    const float* Xp = X + ((size_t)b * SS + row0) * DM;
    const float* Wp = W + (size_t)h * DM * DK;

    float acc[4][4] = {};

    for (int d0 = 0; d0 < DM; d0 += 64) {
        #pragma unroll
        for (int p = 0; p < 4; ++p) {
            const int r = p * 16 + ty;
            const int c = tx * 4;
            float4 xv = *(const float4*)(Xp + (size_t)r * DM + d0 + c);
            Xs[c + 0][r] = xv.x; Xs[c + 1][r] = xv.y;
            Xs[c + 2][r] = xv.z; Xs[c + 3][r] = xv.w;
            *(float4*)&Ws[r][c] = *(const float4*)(Wp + (size_t)(d0 + r) * DK + c);
        }
        __syncthreads();
        #pragma unroll 8
        for (int kk = 0; kk < 64; ++kk) {
            const float4 a4 = *(const float4*)&Xs[kk][ty * 4];
            const float4 w4 = *(const float4*)&Ws[kk][tx * 4];
            const float av[4] = {a4.x, a4.y, a4.z, a4.w};
            const float wv[4] = {w4.x, w4.y, w4.z, w4.w};
            #pragma unroll
            for (int i = 0; i < 4; ++i)
                #pragma unroll
                for (int j = 0; j < 4; ++j)
                    acc[i][j] = fmaf(av[i], wv[j], acc[i][j]);
        }
        __syncthreads();
    }

    const float4 bv4 = *(const float4*)(bias + h * DK + tx * 4);
    const float bb[4] = {bv4.x, bv4.y, bv4.z, bv4.w};
    float* op = out + ((size_t)(b * HH + h) * SS + row0) * DK;
    #pragma unroll
    for (int i = 0; i < 4; ++i) {
        const int r = ty * 4 + i;
        float4 o;
        o.x = acc[i][0] + bb[0]; o.y = acc[i][1] + bb[1];
        o.z = acc[i][2] + bb[2]; o.w = acc[i][3] + bb[3];
        *(float4*)(op + (size_t)r * DK + tx * 4) = o;
    }
}

// ---------------------------------------------------------------------------
// attn_kernel: flash attention over one (b,h) and one 64-row Q tile.
// scores = QW @ KW^T (no /sqrt(dk) per reference!), online softmax,
// O = (softmax @ VW) / 128, written into concat layout CC[b,s,h*64+v].
// ---------------------------------------------------------------------------
__global__ __launch_bounds__(256) void attn_kernel(
    const float* __restrict__ QW,   // [B*H, S, DK]
    const float* __restrict__ KW,
    const float* __restrict__ VW,
    float* __restrict__ CC)         // [B, S, H*DK]
{
    __shared__ float Qs[64][PADW];  // [kk][row]
    __shared__ float Ks[64][PADW];  // [kk][col=t]
    __shared__ float Vs[64][PADW];  // [t][v]
    __shared__ float Ps[64][PADW];  // [t][row]
    const int tid = threadIdx.x;
    const int tx = tid & 15, ty = tid >> 4;
    const int bh = blockIdx.y;
    const int b = bh / HH, h = bh % HH;
    const int row0 = blockIdx.x * 64;
    const float* Qp = QW + ((size_t)bh * SS + row0) * DK;
    const float* Kp = KW + (size_t)bh * SS * DK;
    const float* Vp = VW + (size_t)bh * SS * DK;

    // stage Q transposed
    #pragma unroll
    for (int p = 0; p < 4; ++p) {
        const int r = p * 16 + ty, c = tx * 4;
        float4 qv = *(const float4*)(Qp + (size_t)r * DK + c);
        Qs[c + 0][r] = qv.x; Qs[c + 1][r] = qv.y;
        Qs[c + 2][r] = qv.z; Qs[c + 3][r] = qv.w;
    }

    float o[4][4] = {};
    float m[4], l[4];
    #pragma unroll
    for (int i = 0; i < 4; ++i) { m[i] = -1e30f; l[i] = 0.f; }
    __syncthreads();

    for (int t0 = 0; t0 < SS; t0 += 64) {
        // stage K transposed, V natural
        #pragma unroll
        for (int p = 0; p < 4; ++p) {
            const int r = p * 16 + ty, c = tx * 4;
            float4 kv = *(const float4*)(Kp + (size_t)(t0 + r) * DK + c);
            Ks[c + 0][r] = kv.x; Ks[c + 1][r] = kv.y;
            Ks[c + 2][r] = kv.z; Ks[c + 3][r] = kv.w;
            *(float4*)&Vs[r][c] = *(const float4*)(Vp + (size_t)(t0 + r) * DK + c);
        }
        __syncthreads();

        // S = Q @ K^T  (64x64x64)
        float s[4][4] = {};
        #pragma unroll 8
        for (int kk = 0; kk < 64; ++kk) {
            const float4 a4 = *(const float4*)&Qs[kk][ty * 4];
            const float4 k4 = *(const float4*)&Ks[kk][tx * 4];
            const float av[4] = {a4.x, a4.y, a4.z, a4.w};
            const float kv[4] = {k4.x, k4.y, k4.z, k4.w};
            #pragma unroll
            for (int i = 0; i < 4; ++i)
                #pragma unroll
                for (int j = 0; j < 4; ++j)
                    s[i][j] = fmaf(av[i], kv[j], s[i][j]);
        }

        // online softmax (row stats shared across the 16 tx threads of a row)
        #pragma unroll
        for (int i = 0; i < 4; ++i) {
            float mx = fmaxf(fmaxf(s[i][0], s[i][1]), fmaxf(s[i][2], s[i][3]));
            #pragma unroll
            for (int d = 1; d < 16; d <<= 1)
                mx = fmaxf(mx, __shfl_xor(mx, d, 64));
            const float mn = fmaxf(m[i], mx);
            const float scale = __expf(m[i] - mn);
            m[i] = mn;
            float rs = 0.f;
            #pragma unroll
            for (int j = 0; j < 4; ++j) {
                s[i][j] = __expf(s[i][j] - mn);
                rs += s[i][j];
            }
            #pragma unroll
            for (int d = 1; d < 16; d <<= 1)
                rs += __shfl_xor(rs, d, 64);
            l[i] = l[i] * scale + rs;
            #pragma unroll
            for (int j = 0; j < 4; ++j) o[i][j] *= scale;
        }

        // write P transposed: Ps[t_local][row]
        #pragma unroll
        for (int i = 0; i < 4; ++i)
            #pragma unroll
            for (int j = 0; j < 4; ++j)
                Ps[tx * 4 + j][ty * 4 + i] = s[i][j];
        __syncthreads();

        // O += P @ V  (64x64x64)
        #pragma unroll 8
        for (int t = 0; t < 64; ++t) {
            const float4 a4 = *(const float4*)&Ps[t][ty * 4];
            const float4 v4 = *(const float4*)&Vs[t][tx * 4];
            const float av[4] = {a4.x, a4.y, a4.z, a4.w};
            const float vv[4] = {v4.x, v4.y, v4.z, v4.w};
            #pragma unroll
            for (int i = 0; i < 4; ++i)
                #pragma unroll
                for (int j = 0; j < 4; ++j)
                    o[i][j] = fmaf(av[i], vv[j], o[i][j]);
        }
        __syncthreads();
    }

    // epilogue: concat layout, with softmax * 1/(2*DK) = 1/128 scaling
    float* cp = CC + ((size_t)b * SS + row0) * (HH * DK) + h * DK;
    #pragma unroll
    for (int i = 0; i < 4; ++i) {
        const int r = ty * 4 + i;
        const float inv = 1.0f / (l[i] * 128.0f);
        float4 ov;
        ov.x = o[i][0] * inv; ov.y = o[i][1] * inv;
        ov.z = o[i][2] * inv; ov.w = o[i][3] * inv;
        *(float4*)(cp + (size_t)r * (HH * DK) + tx * 4) = ov;
    }
}

// ---------------------------------------------------------------------------
// outproj_kernel: out[r, c] = CC[r,:] @ Wo[:,c] + bo[c]   (4096x1024x1024)
// ---------------------------------------------------------------------------
__global__ __launch_bounds__(256) void outproj_kernel(
    const float* __restrict__ Xc,   // [B*S, DM]
    const float* __restrict__ Wo,   // [DM, DM]
    const float* __restrict__ bo,   // [DM]
    float* __restrict__ out)        // [B*S, DM]
{
    __shared__ float Xs[64][PADW];
    __shared__ float Ws[64][PADW];
    const int tid = threadIdx.x;
    const int tx = tid & 15, ty = tid >> 4;
    const int row0 = blockIdx.x * 64;
    const int col0 = blockIdx.y * 64;
    const float* Xp = Xc + (size_t)row0 * DM;

    float acc[4][4] = {};

    for (int d0 = 0; d0 < DM; d0 += 64) {
        #pragma unroll
        for (int p = 0; p < 4; ++p) {
            const int r = p * 16 + ty;
            const int c = tx * 4;
            float4 xv = *(const float4*)(Xp + (size_t)r * DM + d0 + c);
            Xs[c + 0][r] = xv.x; Xs[c + 1][r] = xv.y;
            Xs[c + 2][r] = xv.z; Xs[c + 3][r] = xv.w;
            *(float4*)&Ws[r][c] = *(const float4*)(Wo + (size_t)(d0 + r) * DM + col0 + c);
        }
        __syncthreads();
        #pragma unroll 8
        for (int kk = 0; kk < 64; ++kk) {
            const float4 a4 = *(const float4*)&Xs[kk][ty * 4];
            const float4 w4 = *(const float4*)&Ws[kk][tx * 4];
            const float av[4] = {a4.x, a4.y, a4.z, a4.w};
            const float wv[4] = {w4.x, w4.y, w4.z, w4.w};
            #pragma unroll
            for (int i = 0; i < 4; ++i)
                #pragma unroll
                for (int j = 0; j < 4; ++j)
                    acc[i][j] = fmaf(av[i], wv[j], acc[i][j]);
        }
        __syncthreads();
    }

    const float4 bv4 = *(const float4*)(bo + col0 + tx * 4);
    const float bb[4] = {bv4.x, bv4.y, bv4.z, bv4.w};
    #pragma unroll
    for (int i = 0; i < 4; ++i) {
        const int r = row0 + ty * 4 + i;
        float4 ov;
        ov.x = acc[i][0] + bb[0]; ov.y = acc[i][1] + bb[1];
        ov.z = acc[i][2] + bb[2]; ov.w = acc[i][3] + bb[3];
        *(float4*)(out + (size_t)r * DM + col0 + tx * 4) = ov;
    }
}

extern "C" void kernel_launch(void* const* d_in, const int* in_sizes, int n_in,
                              void* d_out, int out_size, void* d_ws, size_t ws_size,
                              hipStream_t stream) {
    const float* Q  = (const float*)d_in[0];
    const float* K  = (const float*)d_in[1];
    const float* V  = (const float*)d_in[2];
    const float* Wq = (const float*)d_in[3];
    const float* bq = (const float*)d_in[4];
    const float* Wk = (const float*)d_in[5];
    const float* bk = (const float*)d_in[6];
    const float* Wv = (const float*)d_in[7];
    const float* bv = (const float*)d_in[8];
    const float* Wo = (const float*)d_in[9];
    const float* bo = (const float*)d_in[10];
    float* out = (float*)d_out;

    // workspace layout: QW | KW | VW | CC   (4 x 16.78 MB = 67.1 MB)
    const size_t per = (size_t)BB * HH * SS * DK;
    float* QWp = (float*)d_ws;
    float* KWp = QWp + per;
    float* VWp = KWp + per;
    float* CC  = VWp + per;

    dim3 blk(256);
    dim3 gproj(SS / 64, BB * HH);
    hipLaunchKernelGGL(proj_kernel, gproj, blk, 0, stream, Q, Wq, bq, QWp);
    hipLaunchKernelGGL(proj_kernel, gproj, blk, 0, stream, K, Wk, bk, KWp);
    hipLaunchKernelGGL(proj_kernel, gproj, blk, 0, stream, V, Wv, bv, VWp);

    dim3 gattn(SS / 64, BB * HH);
    hipLaunchKernelGGL(attn_kernel, gattn, blk, 0, stream, QWp, KWp, VWp, CC);

    dim3 gout((BB * SS) / 64, DM / 64);
    hipLaunchKernelGGL(outproj_kernel, gout, blk, 0, stream, CC, Wo, bo, out);
}

// Round 2
// 244.378 us; speedup vs baseline: 4.3846x; 4.3846x over previous
//
#include <hip/hip_runtime.h>

#define BB 2
#define SS 2048
#define DM 1024
#define HH 16
#define DK 64

typedef __attribute__((ext_vector_type(8))) short short8;
typedef __attribute__((ext_vector_type(4))) float f32x4;

#define MFMA16(a, b, c) __builtin_amdgcn_mfma_f32_16x16x32_bf16(a, b, c, 0, 0, 0)

static __device__ __forceinline__ unsigned short f2bf(float f) {
    unsigned u = __builtin_bit_cast(unsigned, f);
    u += 0x7fffu + ((u >> 16) & 1u);   // RNE
    return (unsigned short)(u >> 16);
}

// ---------------------------------------------------------------------------
// fp32 -> bf16 elementwise (vectorized 8/thread)
// ---------------------------------------------------------------------------
__global__ __launch_bounds__(256) void cvt_kernel(const float* __restrict__ in,
                                                  unsigned short* __restrict__ out) {
    const int i = (blockIdx.x * 256 + threadIdx.x) * 8;
    float4 a = *(const float4*)(in + i);
    float4 b = *(const float4*)(in + i + 4);
    union { unsigned short u[8]; uint4 v; } x;
    x.u[0] = f2bf(a.x); x.u[1] = f2bf(a.y); x.u[2] = f2bf(a.z); x.u[3] = f2bf(a.w);
    x.u[4] = f2bf(b.x); x.u[5] = f2bf(b.y); x.u[6] = f2bf(b.z); x.u[7] = f2bf(b.w);
    *(uint4*)(out + i) = x.v;
}

// ---------------------------------------------------------------------------
// per-head transpose: in fp32 [R][C] (head stride ihs) -> out bf16 [C][R]
// ---------------------------------------------------------------------------
__global__ __launch_bounds__(256) void wtrans_kernel(const float* __restrict__ in,
                                                     unsigned short* __restrict__ out,
                                                     int R, int C, int ihs, int ohs) {
    __shared__ float t[64][65];
    const int r0 = blockIdx.x * 64, c0 = blockIdx.y * 64, h = blockIdx.z;
    const float* ip = in + (size_t)h * ihs;
    unsigned short* op = out + (size_t)h * ohs;
    const int lr = threadIdx.x & 63, gg = threadIdx.x >> 6;
    #pragma unroll
    for (int p = 0; p < 16; ++p) {
        const int r = p * 4 + gg;
        t[r][lr] = ip[(size_t)(r0 + r) * C + c0 + lr];
    }
    __syncthreads();
    #pragma unroll
    for (int p = 0; p < 16; ++p) {
        const int c = p * 4 + gg;
        op[(size_t)(c0 + c) * R + r0 + lr] = f2bf(t[lr][c]);
    }
}

// ---------------------------------------------------------------------------
// bf16 MFMA GEMM: C[M][1024] = A[M][1024] * Bt[1024][1024]^T + bias
// 128x128 tile, 256 threads = 4 waves, 64x64 per wave, 16x16x32 MFMA.
// MODE 0: store bf16 C[r][c]
// MODE 1: store bf16 transposed per-head: VWt[((b*16+h)*64+v)*2048 + s]
// MODE 2: store fp32 C[r][c]
// ---------------------------------------------------------------------------
template <int MODE>
__global__ __launch_bounds__(256) void gemm_kernel(
    const unsigned short* __restrict__ A,
    const unsigned short* __restrict__ Bt,
    const float* __restrict__ bias,
    void* __restrict__ Cout, int M) {
    __shared__ unsigned short As[128 * 64];
    __shared__ unsigned short Bs[128 * 64];
    const int tid = threadIdx.x;
    const int r0 = blockIdx.x * 128, n0 = blockIdx.y * 128;
    const int w = tid >> 6, lane = tid & 63, lr = lane & 15, lg = lane >> 4;
    const int wr = (w >> 1) * 64, wc = (w & 1) * 64;

    const f32x4 zf = {0.f, 0.f, 0.f, 0.f};
    f32x4 acc[4][4];
    #pragma unroll
    for (int mi = 0; mi < 4; ++mi)
        #pragma unroll
        for (int ni = 0; ni < 4; ++ni) acc[mi][ni] = zf;

    for (int k0 = 0; k0 < DM; k0 += 64) {
        #pragma unroll
        for (int i = 0; i < 4; ++i) {
            const int ck = tid + i * 256;
            const int row = ck >> 3, c8 = (ck & 7) * 8;
            *(uint4*)&As[row * 64 + c8] =
                *(const uint4*)&A[(size_t)(r0 + row) * DM + k0 + c8];
            *(uint4*)&Bs[row * 64 + c8] =
                *(const uint4*)&Bt[(size_t)(n0 + row) * DM + k0 + c8];
        }
        __syncthreads();
        #pragma unroll
        for (int kc = 0; kc < 2; ++kc) {
            short8 a[4], b[4];
            #pragma unroll
            for (int i = 0; i < 4; ++i) {
                a[i] = *(const short8*)&As[(wr + i * 16 + lr) * 64 + kc * 32 + lg * 8];
                b[i] = *(const short8*)&Bs[(wc + i * 16 + lr) * 64 + kc * 32 + lg * 8];
            }
            #pragma unroll
            for (int mi = 0; mi < 4; ++mi)
                #pragma unroll
                for (int ni = 0; ni < 4; ++ni)
                    acc[mi][ni] = MFMA16(a[mi], b[ni], acc[mi][ni]);
        }
        __syncthreads();
    }

    #pragma unroll
    for (int ni = 0; ni < 4; ++ni) {
        const int col = n0 + wc + ni * 16 + lr;
        const float bb = bias[col];
        #pragma unroll
        for (int mi = 0; mi < 4; ++mi) {
            const int rbase = r0 + wr + mi * 16 + lg * 4;
            const f32x4 v = acc[mi][ni];
            if (MODE == 0) {
                unsigned short* C = (unsigned short*)Cout;
                #pragma unroll
                for (int j = 0; j < 4; ++j)
                    C[(size_t)(rbase + j) * DM + col] = f2bf(v[j] + bb);
            } else if (MODE == 1) {
                unsigned short* C = (unsigned short*)Cout;
                const int b = rbase >> 11, s = rbase & (SS - 1);
                const int h = col >> 6, vv = col & 63;
                union { unsigned short u[4]; unsigned long long q; } x;
                #pragma unroll
                for (int j = 0; j < 4; ++j) x.u[j] = f2bf(v[j] + bb);
                *(unsigned long long*)&C[((size_t)(b * HH + h) * 64 + vv) * SS + s] = x.q;
            } else {
                float* C = (float*)Cout;
                #pragma unroll
                for (int j = 0; j < 4; ++j)
                    C[(size_t)(rbase + j) * DM + col] = v[j] + bb;
            }
        }
    }
}

// ---------------------------------------------------------------------------
// MFMA flash attention. Per block: one (b,h), 64 Q rows. 4 waves x 16-row
// strips. QW/KW in concat layout [b, s, h*64+k]; V pre-transposed
// VWt[(bh*64+v)*2048 + t]. Output CC bf16 concat layout.
// ---------------------------------------------------------------------------
__global__ __launch_bounds__(256) void attn_kernel(
    const unsigned short* __restrict__ QW,
    const unsigned short* __restrict__ KW,
    const unsigned short* __restrict__ VWt,
    unsigned short* __restrict__ CC) {
    __shared__ unsigned short Ks[64 * 72];   // [t_local][k], padded to 72
    __shared__ unsigned short Vs[64 * 72];   // [v][t_local]
    __shared__ unsigned short Ps[64 * 72];   // [q_row][t_local] (also Q staging)
    const int tid = threadIdx.x;
    const int w = tid >> 6, lane = tid & 63, lr = lane & 15, lg = lane >> 4;
    const int bh = blockIdx.y, b = bh >> 4, h = bh & 15;
    const int row0 = blockIdx.x * 64;
    const unsigned short* Qp = QW + ((size_t)b * SS + row0) * DM + h * DK;
    const unsigned short* Kp = KW + (size_t)b * SS * DM + h * DK;
    const unsigned short* Vt = VWt + (size_t)bh * 64 * SS;

    // stage Q tile into Ps, then hoist this wave's A-fragments to registers
    #pragma unroll
    for (int i = 0; i < 2; ++i) {
        const int ck = tid + i * 256;
        const int row = ck >> 3, c8 = (ck & 7) * 8;
        *(uint4*)&Ps[row * 72 + c8] = *(const uint4*)&Qp[(size_t)row * DM + c8];
    }
    __syncthreads();
    short8 q[2];
    #pragma unroll
    for (int kc = 0; kc < 2; ++kc)
        q[kc] = *(const short8*)&Ps[(w * 16 + lr) * 72 + kc * 32 + lg * 8];

    const f32x4 zf = {0.f, 0.f, 0.f, 0.f};
    f32x4 o[4];
    float m[4], l[4];
    #pragma unroll
    for (int n = 0; n < 4; ++n) o[n] = zf;
    #pragma unroll
    for (int j = 0; j < 4; ++j) { m[j] = -1e30f; l[j] = 0.f; }

    for (int t0 = 0; t0 < SS; t0 += 64) {
        // stage K [t][k] and V^T [v][t]
        #pragma unroll
        for (int i = 0; i < 2; ++i) {
            const int ck = tid + i * 256;
            const int row = ck >> 3, c8 = (ck & 7) * 8;
            *(uint4*)&Ks[row * 72 + c8] =
                *(const uint4*)&Kp[(size_t)(t0 + row) * DM + c8];
            *(uint4*)&Vs[row * 72 + c8] =
                *(const uint4*)&Vt[(size_t)row * SS + t0 + c8];
        }
        __syncthreads();

        // S strip = Q(16 rows) x K^T(64 cols)
        f32x4 s[4];
        #pragma unroll
        for (int n = 0; n < 4; ++n) s[n] = zf;
        #pragma unroll
        for (int kc = 0; kc < 2; ++kc) {
            #pragma unroll
            for (int n = 0; n < 4; ++n) {
                const short8 kf =
                    *(const short8*)&Ks[(n * 16 + lr) * 72 + kc * 32 + lg * 8];
                s[n] = MFMA16(q[kc], kf, s[n]);
            }
        }

        // online softmax: lane holds rows lg*4+j (4), cols n*16+lr (4)
        #pragma unroll
        for (int j = 0; j < 4; ++j) {
            float rm = fmaxf(fmaxf(s[0][j], s[1][j]), fmaxf(s[2][j], s[3][j]));
            rm = fmaxf(rm, __shfl_xor(rm, 1, 64));
            rm = fmaxf(rm, __shfl_xor(rm, 2, 64));
            rm = fmaxf(rm, __shfl_xor(rm, 4, 64));
            rm = fmaxf(rm, __shfl_xor(rm, 8, 64));
            const float mn = fmaxf(m[j], rm);
            const float sc = __expf(m[j] - mn);
            m[j] = mn;
            float rs = 0.f;
            #pragma unroll
            for (int n = 0; n < 4; ++n) {
                const float e = __expf(s[n][j] - mn);
                s[n][j] = e;
                rs += e;
            }
            rs += __shfl_xor(rs, 1, 64);
            rs += __shfl_xor(rs, 2, 64);
            rs += __shfl_xor(rs, 4, 64);
            rs += __shfl_xor(rs, 8, 64);
            l[j] = l[j] * sc + rs;
            #pragma unroll
            for (int n = 0; n < 4; ++n) o[n][j] *= sc;
        }

        // P (bf16) -> wave-local LDS strip rows [16w, 16w+16)
        #pragma unroll
        for (int n = 0; n < 4; ++n)
            #pragma unroll
            for (int j = 0; j < 4; ++j)
                Ps[(w * 16 + lg * 4 + j) * 72 + n * 16 + lr] = f2bf(s[n][j]);

        // O += P x V  (wave-local Ps read; Vs barrier already passed)
        #pragma unroll
        for (int kc = 0; kc < 2; ++kc) {
            const short8 pa =
                *(const short8*)&Ps[(w * 16 + lr) * 72 + kc * 32 + lg * 8];
            #pragma unroll
            for (int n = 0; n < 4; ++n) {
                const short8 vf =
                    *(const short8*)&Vs[(n * 16 + lr) * 72 + kc * 32 + lg * 8];
                o[n] = MFMA16(pa, vf, o[n]);
            }
        }
        __syncthreads();   // protect Ks/Vs for next tile's staging
    }

    // epilogue: softmax/(2*DK) scaling, bf16 concat layout
    unsigned short* cp = CC + ((size_t)b * SS + row0) * DM + h * DK;
    #pragma unroll
    for (int j = 0; j < 4; ++j) {
        const float inv = 1.0f / (l[j] * 128.0f);
        #pragma unroll
        for (int n = 0; n < 4; ++n)
            cp[(size_t)(w * 16 + lg * 4 + j) * DM + n * 16 + lr] =
                f2bf(o[n][j] * inv);
    }
}

extern "C" void kernel_launch(void* const* d_in, const int* in_sizes, int n_in,
                              void* d_out, int out_size, void* d_ws, size_t ws_size,
                              hipStream_t stream) {
    const float* Q  = (const float*)d_in[0];
    const float* K  = (const float*)d_in[1];
    const float* V  = (const float*)d_in[2];
    const float* Wq = (const float*)d_in[3];
    const float* bq = (const float*)d_in[4];
    const float* Wk = (const float*)d_in[5];
    const float* bk = (const float*)d_in[6];
    const float* Wv = (const float*)d_in[7];
    const float* bv = (const float*)d_in[8];
    const float* Wo = (const float*)d_in[9];
    const float* bo = (const float*)d_in[10];
    float* out = (float*)d_out;

    // workspace (bf16/ushort units), ~58.8 MB total
    unsigned short* ws = (unsigned short*)d_ws;
    const size_t MK = (size_t)BB * SS * DM;        // 4096*1024
    const size_t WK = (size_t)DM * DM;             // 1024*1024
    unsigned short* Qb  = ws;
    unsigned short* Kb  = Qb + MK;
    unsigned short* Vb  = Kb + MK;
    unsigned short* Wqt = Vb + MK;
    unsigned short* Wkt = Wqt + WK;
    unsigned short* Wvt = Wkt + WK;
    unsigned short* Wot = Wvt + WK;
    unsigned short* QWp = Wot + WK;
    unsigned short* KWp = QWp + MK;
    unsigned short* VWt = KWp + MK;
    unsigned short* CCp = Qb;   // Qb dead after Q-projection

    dim3 blk(256);
    const int M = BB * SS;

    hipLaunchKernelGGL(cvt_kernel, dim3(MK / 2048), blk, 0, stream, Q, Qb);
    hipLaunchKernelGGL(cvt_kernel, dim3(MK / 2048), blk, 0, stream, K, Kb);
    hipLaunchKernelGGL(cvt_kernel, dim3(MK / 2048), blk, 0, stream, V, Vb);

    hipLaunchKernelGGL(wtrans_kernel, dim3(16, 1, 16), blk, 0, stream,
                       Wq, Wqt, DM, DK, DM * DK, DK * DM);
    hipLaunchKernelGGL(wtrans_kernel, dim3(16, 1, 16), blk, 0, stream,
                       Wk, Wkt, DM, DK, DM * DK, DK * DM);
    hipLaunchKernelGGL(wtrans_kernel, dim3(16, 1, 16), blk, 0, stream,
                       Wv, Wvt, DM, DK, DM * DK, DK * DM);
    hipLaunchKernelGGL(wtrans_kernel, dim3(16, 16, 1), blk, 0, stream,
                       Wo, Wot, DM, DM, 0, 0);

    hipLaunchKernelGGL((gemm_kernel<0>), dim3(M / 128, 8), blk, 0, stream,
                       Qb, Wqt, bq, (void*)QWp, M);
    hipLaunchKernelGGL((gemm_kernel<0>), dim3(M / 128, 8), blk, 0, stream,
                       Kb, Wkt, bk, (void*)KWp, M);
    hipLaunchKernelGGL((gemm_kernel<1>), dim3(M / 128, 8), blk, 0, stream,
                       Vb, Wvt, bv, (void*)VWt, M);

    hipLaunchKernelGGL(attn_kernel, dim3(SS / 64, BB * HH), blk, 0, stream,
                       QWp, KWp, VWt, CCp);

    hipLaunchKernelGGL((gemm_kernel<2>), dim3(M / 128, 8), blk, 0, stream,
                       CCp, Wot, bo, (void*)out, M);
}

// Round 3
// 206.787 us; speedup vs baseline: 5.1817x; 1.1818x over previous
//
#include <hip/hip_runtime.h>

#define BB 2
#define SS 2048
#define DM 1024
#define HH 16
#define DK 64

typedef __attribute__((ext_vector_type(8))) short short8;
typedef __attribute__((ext_vector_type(4))) float f32x4;
typedef __attribute__((ext_vector_type(16))) float f32x16;

#define MFMA16(a, b, c) __builtin_amdgcn_mfma_f32_16x16x32_bf16(a, b, c, 0, 0, 0)
#define MFMA32(a, b, c) __builtin_amdgcn_mfma_f32_32x32x16_bf16(a, b, c, 0, 0, 0)

static __device__ __forceinline__ unsigned short f2bf(float f) {
    unsigned u = __builtin_bit_cast(unsigned, f);
    u += 0x7fffu + ((u >> 16) & 1u);   // RNE
    return (unsigned short)(u >> 16);
}

static __device__ __forceinline__ unsigned cvtpk(float lo, float hi2) {
    unsigned r;
    asm("v_cvt_pk_bf16_f32 %0, %1, %2" : "=v"(r) : "v"(lo), "v"(hi2));
    return r;
}

// ---------------------------------------------------------------------------
// fp32 -> bf16 elementwise (vectorized 8/thread)
// ---------------------------------------------------------------------------
__global__ __launch_bounds__(256) void cvt_kernel(const float* __restrict__ in,
                                                  unsigned short* __restrict__ out) {
    const int i = (blockIdx.x * 256 + threadIdx.x) * 8;
    float4 a = *(const float4*)(in + i);
    float4 b = *(const float4*)(in + i + 4);
    union { unsigned short u[8]; uint4 v; } x;
    x.u[0] = f2bf(a.x); x.u[1] = f2bf(a.y); x.u[2] = f2bf(a.z); x.u[3] = f2bf(a.w);
    x.u[4] = f2bf(b.x); x.u[5] = f2bf(b.y); x.u[6] = f2bf(b.z); x.u[7] = f2bf(b.w);
    *(uint4*)(out + i) = x.v;
}

// ---------------------------------------------------------------------------
// per-head transpose: in fp32 [R][C] (head stride ihs) -> out bf16 [C][R]
// ---------------------------------------------------------------------------
__global__ __launch_bounds__(256) void wtrans_kernel(const float* __restrict__ in,
                                                     unsigned short* __restrict__ out,
                                                     int R, int C, int ihs, int ohs) {
    __shared__ float t[64][65];
    const int r0 = blockIdx.x * 64, c0 = blockIdx.y * 64, h = blockIdx.z;
    const float* ip = in + (size_t)h * ihs;
    unsigned short* op = out + (size_t)h * ohs;
    const int lr = threadIdx.x & 63, gg = threadIdx.x >> 6;
    #pragma unroll
    for (int p = 0; p < 16; ++p) {
        const int r = p * 4 + gg;
        t[r][lr] = ip[(size_t)(r0 + r) * C + c0 + lr];
    }
    __syncthreads();
    #pragma unroll
    for (int p = 0; p < 16; ++p) {
        const int c = p * 4 + gg;
        op[(size_t)(c0 + c) * R + r0 + lr] = f2bf(t[lr][c]);
    }
}

// ---------------------------------------------------------------------------
// bf16 MFMA GEMM: C[M][1024] = A[M][1024] * Bt[1024][1024]^T + bias
// 128x128 tile, 256 threads = 4 waves, 64x64 per wave, 16x16x32 MFMA.
// MODE 0: store bf16 C[r][c]
// MODE 1: store bf16 transposed per-head: VWt[((b*16+h)*64+v)*2048 + s]
// MODE 2: store fp32 C[r][c]
// ---------------------------------------------------------------------------
template <int MODE>
__global__ __launch_bounds__(256) void gemm_kernel(
    const unsigned short* __restrict__ A,
    const unsigned short* __restrict__ Bt,
    const float* __restrict__ bias,
    void* __restrict__ Cout, int M) {
    __shared__ unsigned short As[128 * 64];
    __shared__ unsigned short Bs[128 * 64];
    const int tid = threadIdx.x;
    const int r0 = blockIdx.x * 128, n0 = blockIdx.y * 128;
    const int w = tid >> 6, lane = tid & 63, lr = lane & 15, lg = lane >> 4;
    const int wr = (w >> 1) * 64, wc = (w & 1) * 64;

    const f32x4 zf = {0.f, 0.f, 0.f, 0.f};
    f32x4 acc[4][4];
    #pragma unroll
    for (int mi = 0; mi < 4; ++mi)
        #pragma unroll
        for (int ni = 0; ni < 4; ++ni) acc[mi][ni] = zf;

    for (int k0 = 0; k0 < DM; k0 += 64) {
        #pragma unroll
        for (int i = 0; i < 4; ++i) {
            const int ck = tid + i * 256;
            const int row = ck >> 3, c8 = (ck & 7) * 8;
            *(uint4*)&As[row * 64 + c8] =
                *(const uint4*)&A[(size_t)(r0 + row) * DM + k0 + c8];
            *(uint4*)&Bs[row * 64 + c8] =
                *(const uint4*)&Bt[(size_t)(n0 + row) * DM + k0 + c8];
        }
        __syncthreads();
        #pragma unroll
        for (int kc = 0; kc < 2; ++kc) {
            short8 a[4], b[4];
            #pragma unroll
            for (int i = 0; i < 4; ++i) {
                a[i] = *(const short8*)&As[(wr + i * 16 + lr) * 64 + kc * 32 + lg * 8];
                b[i] = *(const short8*)&Bs[(wc + i * 16 + lr) * 64 + kc * 32 + lg * 8];
            }
            #pragma unroll
            for (int mi = 0; mi < 4; ++mi)
                #pragma unroll
                for (int ni = 0; ni < 4; ++ni)
                    acc[mi][ni] = MFMA16(a[mi], b[ni], acc[mi][ni]);
        }
        __syncthreads();
    }

    #pragma unroll
    for (int ni = 0; ni < 4; ++ni) {
        const int col = n0 + wc + ni * 16 + lr;
        const float bb = bias[col];
        #pragma unroll
        for (int mi = 0; mi < 4; ++mi) {
            const int rbase = r0 + wr + mi * 16 + lg * 4;
            const f32x4 v = acc[mi][ni];
            if (MODE == 0) {
                unsigned short* C = (unsigned short*)Cout;
                #pragma unroll
                for (int j = 0; j < 4; ++j)
                    C[(size_t)(rbase + j) * DM + col] = f2bf(v[j] + bb);
            } else if (MODE == 1) {
                unsigned short* C = (unsigned short*)Cout;
                const int b = rbase >> 11, s = rbase & (SS - 1);
                const int h = col >> 6, vv = col & 63;
                union { unsigned short u[4]; unsigned long long q; } x;
                #pragma unroll
                for (int j = 0; j < 4; ++j) x.u[j] = f2bf(v[j] + bb);
                *(unsigned long long*)&C[((size_t)(b * HH + h) * 64 + vv) * SS + s] = x.q;
            } else {
                float* C = (float*)Cout;
                #pragma unroll
                for (int j = 0; j < 4; ++j)
                    C[(size_t)(rbase + j) * DM + col] = v[j] + bb;
            }
        }
    }
}

// ---------------------------------------------------------------------------
// MFMA flash attention, swapped-operand 32x32x16 form.
// Block: one (b,h), 128 q rows; 4 waves x 32 q-rows each. KV tile = 64.
// QK^T: S[k][q] = mfma(K_frag, Q_frag)  -> lane owns q = lane&31, 32 scores.
// No max subtraction (scores bounded ~|16| << 88); l-reduce deferred to end.
// P -> bf16 in registers (cvt_pk + half-exchange), PV: O^T = mfma(V^T, P).
// K/V LDS tiles XOR-swizzled: byte ^= (row&7)<<4 (ushort idx ^ (row&7)<<3).
// ---------------------------------------------------------------------------
#define FRAG(buf, row, col) \
    (*(const short8*)&buf[(row) * 64 + ((col) ^ (((row) & 7) << 3))])

__global__ __launch_bounds__(256) void attn_kernel(
    const unsigned short* __restrict__ QW,   // [B, S, H*64] bf16 concat
    const unsigned short* __restrict__ KW,   // [B, S, H*64]
    const unsigned short* __restrict__ VWt,  // [B*H, 64, S]
    unsigned short* __restrict__ CC) {       // [B, S, H*64]
    __shared__ unsigned short Ks[64 * 64];   // [kpos][d], swizzled
    __shared__ unsigned short Vs[64 * 64];   // [v][t],   swizzled
    const int tid = threadIdx.x;
    const int w = tid >> 6, lane = tid & 63;
    const int ql = lane & 31, hi = lane >> 5;
    const int bh = blockIdx.y, b = bh >> 4, h = bh & 15;
    const int row0 = blockIdx.x * 128;
    const int q = row0 + w * 32 + ql;

    // Q fragments: lane holds Q[q][kc*16 + hi*8 + (0..7)]
    short8 qf[4];
    const unsigned short* Qp = QW + ((size_t)b * SS + q) * DM + h * DK;
    #pragma unroll
    for (int kc = 0; kc < 4; ++kc)
        qf[kc] = *(const short8*)(Qp + kc * 16 + hi * 8);

    const unsigned short* Kp = KW + (size_t)b * SS * DM + h * DK;
    const unsigned short* Vt = VWt + (size_t)bh * 64 * SS;

    const f32x16 z16 = {0.f};
    f32x16 o0 = z16, o1 = z16;
    float lacc = 0.f;

    for (int t0 = 0; t0 < SS; t0 += 64) {
        // stage K [t][d] and V^T [v][t], swizzled
        #pragma unroll
        for (int r2 = 0; r2 < 2; ++r2) {
            const int idx = tid + r2 * 256;
            const int row = idx >> 3, c8 = idx & 7;
            const int sw = (c8 * 8) ^ ((row & 7) << 3);
            *(uint4*)&Ks[row * 64 + sw] =
                *(const uint4*)&Kp[(size_t)(t0 + row) * DM + c8 * 8];
            *(uint4*)&Vs[row * 64 + sw] =
                *(const uint4*)&Vt[(size_t)row * SS + t0 + c8 * 8];
        }
        __syncthreads();

        // S[k][q]: two 32-k fragments (kt=0,1) accumulated over 4 d-slices
        f32x16 s0 = z16, s1 = z16;
        #pragma unroll
        for (int kc = 0; kc < 4; ++kc) {
            s0 = MFMA32(FRAG(Ks, ql, kc * 16 + hi * 8), qf[kc], s0);
            s1 = MFMA32(FRAG(Ks, 32 + ql, kc * 16 + hi * 8), qf[kc], s1);
        }

        // exp (no max subtraction) + deferred l accumulation
        #pragma unroll
        for (int r = 0; r < 16; ++r) {
            const float e0 = __expf(s0[r]);
            const float e1 = __expf(s1[r]);
            s0[r] = e0; s1[r] = e1;
            lacc += e0 + e1;
        }

        // P -> bf16 B-fragments: pa[ks] holds P[q][ks*16 + hi*8 + j]
        // lane's p-value at reg r of s{kt}: k = 32kt + 8(r>>2) + 4hi + (r&3)
        short8 pa[4];
        #pragma unroll
        for (int ks = 0; ks < 4; ++ks) {
            const f32x16 sx = (ks < 2) ? s0 : s1;
            const int b0 = (ks & 1) * 8;
            const unsigned x  = cvtpk(sx[b0 + 0], sx[b0 + 1]);
            const unsigned x2 = cvtpk(sx[b0 + 2], sx[b0 + 3]);
            const unsigned y  = cvtpk(sx[b0 + 4], sx[b0 + 5]);
            const unsigned y2 = cvtpk(sx[b0 + 6], sx[b0 + 7]);
            const unsigned xx  = (unsigned)__shfl_xor((int)x, 32, 64);
            const unsigned yy  = (unsigned)__shfl_xor((int)y, 32, 64);
            const unsigned x2x = (unsigned)__shfl_xor((int)x2, 32, 64);
            const unsigned y2x = (unsigned)__shfl_xor((int)y2, 32, 64);
            union { unsigned u[4]; short8 s8; } pk;
            pk.u[0] = hi ? yy  : x;     // k pair 16ks+8hi+0,1
            pk.u[1] = hi ? y2x : x2;    // +2,3
            pk.u[2] = hi ? y   : xx;    // +4,5
            pk.u[3] = hi ? y2  : x2x;   // +6,7
            pa[ks] = pk.s8;
        }

        // O^T[v][q] += V^T x P : A = V^T frag, B = pa
        #pragma unroll
        for (int ks = 0; ks < 4; ++ks) {
            o0 = MFMA32(FRAG(Vs, ql, ks * 16 + hi * 8), pa[ks], o0);
            o1 = MFMA32(FRAG(Vs, 32 + ql, ks * 16 + hi * 8), pa[ks], o1);
        }
        __syncthreads();
    }

    // epilogue: l = own-half sum + other half; scale by 1/(128*l)
    const float lt = lacc + __shfl_xor(lacc, 32, 64);
    const float inv = 1.0f / (lt * 128.0f);
    unsigned short* cp = CC + ((size_t)b * SS + q) * DM + h * DK;
    #pragma unroll
    for (int vt = 0; vt < 2; ++vt) {
        const f32x16 ov = vt ? o1 : o0;
        #pragma unroll
        for (int m2 = 0; m2 < 4; ++m2) {
            union { unsigned short u[4]; unsigned long long q8; } pk;
            #pragma unroll
            for (int c = 0; c < 4; ++c) pk.u[c] = f2bf(ov[m2 * 4 + c] * inv);
            // v = vt*32 + m2*8 + hi*4 + c
            *(unsigned long long*)(cp + vt * 32 + m2 * 8 + hi * 4) = pk.q8;
        }
    }
}

extern "C" void kernel_launch(void* const* d_in, const int* in_sizes, int n_in,
                              void* d_out, int out_size, void* d_ws, size_t ws_size,
                              hipStream_t stream) {
    const float* Q  = (const float*)d_in[0];
    const float* K  = (const float*)d_in[1];
    const float* V  = (const float*)d_in[2];
    const float* Wq = (const float*)d_in[3];
    const float* bq = (const float*)d_in[4];
    const float* Wk = (const float*)d_in[5];
    const float* bk = (const float*)d_in[6];
    const float* Wv = (const float*)d_in[7];
    const float* bv = (const float*)d_in[8];
    const float* Wo = (const float*)d_in[9];
    const float* bo = (const float*)d_in[10];
    float* out = (float*)d_out;

    // workspace (bf16/ushort units)
    unsigned short* ws = (unsigned short*)d_ws;
    const size_t MK = (size_t)BB * SS * DM;        // 4096*1024
    const size_t WK = (size_t)DM * DM;             // 1024*1024
    unsigned short* Qb  = ws;
    unsigned short* Kb  = Qb + MK;
    unsigned short* Vb  = Kb + MK;
    unsigned short* Wqt = Vb + MK;
    unsigned short* Wkt = Wqt + WK;
    unsigned short* Wvt = Wkt + WK;
    unsigned short* Wot = Wvt + WK;
    unsigned short* QWp = Wot + WK;
    unsigned short* KWp = QWp + MK;
    unsigned short* VWt = KWp + MK;
    unsigned short* CCp = Qb;   // Qb dead after Q-projection

    dim3 blk(256);
    const int M = BB * SS;

    hipLaunchKernelGGL(cvt_kernel, dim3(MK / 2048), blk, 0, stream, Q, Qb);
    hipLaunchKernelGGL(cvt_kernel, dim3(MK / 2048), blk, 0, stream, K, Kb);
    hipLaunchKernelGGL(cvt_kernel, dim3(MK / 2048), blk, 0, stream, V, Vb);

    hipLaunchKernelGGL(wtrans_kernel, dim3(16, 1, 16), blk, 0, stream,
                       Wq, Wqt, DM, DK, DM * DK, DK * DM);
    hipLaunchKernelGGL(wtrans_kernel, dim3(16, 1, 16), blk, 0, stream,
                       Wk, Wkt, DM, DK, DM * DK, DK * DM);
    hipLaunchKernelGGL(wtrans_kernel, dim3(16, 1, 16), blk, 0, stream,
                       Wv, Wvt, DM, DK, DM * DK, DK * DM);
    hipLaunchKernelGGL(wtrans_kernel, dim3(16, 16, 1), blk, 0, stream,
                       Wo, Wot, DM, DM, 0, 0);

    hipLaunchKernelGGL((gemm_kernel<0>), dim3(M / 128, 8), blk, 0, stream,
                       Qb, Wqt, bq, (void*)QWp, M);
    hipLaunchKernelGGL((gemm_kernel<0>), dim3(M / 128, 8), blk, 0, stream,
                       Kb, Wkt, bk, (void*)KWp, M);
    hipLaunchKernelGGL((gemm_kernel<1>), dim3(M / 128, 8), blk, 0, stream,
                       Vb, Wvt, bv, (void*)VWt, M);

    hipLaunchKernelGGL(attn_kernel, dim3(SS / 128, BB * HH), blk, 0, stream,
                       QWp, KWp, VWt, CCp);

    hipLaunchKernelGGL((gemm_kernel<2>), dim3(M / 128, 8), blk, 0, stream,
                       CCp, Wot, bo, (void*)out, M);
}

// Round 4
// 165.667 us; speedup vs baseline: 6.4678x; 1.2482x over previous
//
#include <hip/hip_runtime.h>

#define BB 2
#define SS 2048
#define DM 1024
#define HH 16
#define DK 64
#define LOG2E 1.44269504088896340736f

typedef __attribute__((ext_vector_type(8))) short short8;
typedef __attribute__((ext_vector_type(4))) float f32x4;
typedef __attribute__((ext_vector_type(16))) float f32x16;

#define MFMA16(a, b, c) __builtin_amdgcn_mfma_f32_16x16x32_bf16(a, b, c, 0, 0, 0)
#define MFMA32(a, b, c) __builtin_amdgcn_mfma_f32_32x32x16_bf16(a, b, c, 0, 0, 0)

#if __has_builtin(__builtin_amdgcn_exp2f)
#define EXP2(x) __builtin_amdgcn_exp2f(x)
#else
#define EXP2(x) __expf((x) * 0.6931471805599453f)
#endif

static __device__ __forceinline__ unsigned short f2bf(float f) {
    unsigned u = __builtin_bit_cast(unsigned, f);
    u += 0x7fffu + ((u >> 16) & 1u);   // RNE
    return (unsigned short)(u >> 16);
}
static __device__ __forceinline__ float bf2f(unsigned short u) {
    return __builtin_bit_cast(float, ((unsigned)u) << 16);
}

// async global->LDS, 16B per lane; LDS dest must be linear (base + lane*16)
static __device__ __forceinline__ void gld16(const void* g, void* l) {
    __builtin_amdgcn_global_load_lds(
        (const __attribute__((address_space(1))) unsigned int*)g,
        (__attribute__((address_space(3))) unsigned int*)l, 16, 0, 0);
}

// ---------------------------------------------------------------------------
// fp32 -> bf16 for Q,K,V in one launch (blockIdx.y selects matrix)
// ---------------------------------------------------------------------------
__global__ __launch_bounds__(256) void cvt3_kernel(
    const float* __restrict__ p0, const float* __restrict__ p1,
    const float* __restrict__ p2, unsigned short* __restrict__ o0,
    unsigned short* __restrict__ o1, unsigned short* __restrict__ o2) {
    const int m = blockIdx.y;
    const float* in = m == 0 ? p0 : (m == 1 ? p1 : p2);
    unsigned short* out = m == 0 ? o0 : (m == 1 ? o1 : o2);
    const int i = (blockIdx.x * 256 + threadIdx.x) * 8;
    float4 a = *(const float4*)(in + i);
    float4 b = *(const float4*)(in + i + 4);
    union { unsigned short u[8]; uint4 v; } x;
    x.u[0] = f2bf(a.x); x.u[1] = f2bf(a.y); x.u[2] = f2bf(a.z); x.u[3] = f2bf(a.w);
    x.u[4] = f2bf(b.x); x.u[5] = f2bf(b.y); x.u[6] = f2bf(b.z); x.u[7] = f2bf(b.w);
    *(uint4*)(out + i) = x.v;
}

// ---------------------------------------------------------------------------
// per-head transpose: in fp32 [R][C] (head stride ihs) -> out bf16 [C][R]
// ---------------------------------------------------------------------------
__global__ __launch_bounds__(256) void wtrans_kernel(const float* __restrict__ in,
                                                     unsigned short* __restrict__ out,
                                                     int R, int C, int ihs, int ohs) {
    __shared__ float t[64][65];
    const int r0 = blockIdx.x * 64, c0 = blockIdx.y * 64, h = blockIdx.z;
    const float* ip = in + (size_t)h * ihs;
    unsigned short* op = out + (size_t)h * ohs;
    const int lr = threadIdx.x & 63, gg = threadIdx.x >> 6;
    #pragma unroll
    for (int p = 0; p < 16; ++p) {
        const int r = p * 4 + gg;
        t[r][lr] = ip[(size_t)(r0 + r) * C + c0 + lr];
    }
    __syncthreads();
    #pragma unroll
    for (int p = 0; p < 16; ++p) {
        const int c = p * 4 + gg;
        op[(size_t)(c0 + c) * R + r0 + lr] = f2bf(t[lr][c]);
    }
}

// ---------------------------------------------------------------------------
// fused QKV projection GEMM: z = blockIdx.z selects {Q,K,V}.
// C[M][1024] = A[M][1024] * Bt[1024][1024]^T + bias.
// z==0: bf16 store scaled by log2(e) (exp2 domain for attention)
// z==1: bf16 store
// z==2: bf16 transposed per-head store VWt[((b*16+h)*64+v)*2048 + s]
// global_load_lds 16B staging, linear LDS.
// ---------------------------------------------------------------------------
__global__ __launch_bounds__(256) void qkv_gemm_kernel(
    const unsigned short* __restrict__ Qb, const unsigned short* __restrict__ Kb,
    const unsigned short* __restrict__ Vb,
    const unsigned short* __restrict__ Wqt, const unsigned short* __restrict__ Wkt,
    const unsigned short* __restrict__ Wvt,
    const float* __restrict__ bq, const float* __restrict__ bk,
    const float* __restrict__ bv,
    unsigned short* __restrict__ QWp, unsigned short* __restrict__ KWp,
    unsigned short* __restrict__ VWt) {
    __shared__ unsigned short As[128 * 64];
    __shared__ unsigned short Bs[128 * 64];
    const int z = blockIdx.z;
    const unsigned short* A  = z == 0 ? Qb : (z == 1 ? Kb : Vb);
    const unsigned short* Bt = z == 0 ? Wqt : (z == 1 ? Wkt : Wvt);
    const float* bias = z == 0 ? bq : (z == 1 ? bk : bv);
    const int tid = threadIdx.x;
    const int r0 = blockIdx.x * 128, n0 = blockIdx.y * 128;
    const int w = tid >> 6, lane = tid & 63, lr = lane & 15, lg = lane >> 4;
    const int wr = (w >> 1) * 64, wc = (w & 1) * 64;

    const f32x4 zf = {0.f, 0.f, 0.f, 0.f};
    f32x4 acc[4][4];
    #pragma unroll
    for (int mi = 0; mi < 4; ++mi)
        #pragma unroll
        for (int ni = 0; ni < 4; ++ni) acc[mi][ni] = zf;

    for (int k0 = 0; k0 < DM; k0 += 64) {
        #pragma unroll
        for (int i = 0; i < 4; ++i) {
            const int idx = tid + i * 256;
            const int row = idx >> 3, c8 = (idx & 7) * 8;
            gld16(&A[(size_t)(r0 + row) * DM + k0 + c8], &As[idx * 8]);
            gld16(&Bt[(size_t)(n0 + row) * DM + k0 + c8], &Bs[idx * 8]);
        }
        __syncthreads();
        #pragma unroll
        for (int kc = 0; kc < 2; ++kc) {
            short8 a[4], b[4];
            #pragma unroll
            for (int i = 0; i < 4; ++i) {
                a[i] = *(const short8*)&As[(wr + i * 16 + lr) * 64 + kc * 32 + lg * 8];
                b[i] = *(const short8*)&Bs[(wc + i * 16 + lr) * 64 + kc * 32 + lg * 8];
            }
            #pragma unroll
            for (int mi = 0; mi < 4; ++mi)
                #pragma unroll
                for (int ni = 0; ni < 4; ++ni)
                    acc[mi][ni] = MFMA16(a[mi], b[ni], acc[mi][ni]);
        }
        __syncthreads();
    }

    const float scale = (z == 0) ? LOG2E : 1.0f;
    #pragma unroll
    for (int ni = 0; ni < 4; ++ni) {
        const int col = n0 + wc + ni * 16 + lr;
        const float bb = bias[col];
        #pragma unroll
        for (int mi = 0; mi < 4; ++mi) {
            const int rbase = r0 + wr + mi * 16 + lg * 4;
            const f32x4 v = acc[mi][ni];
            if (z == 2) {
                const int b = rbase >> 11, s = rbase & (SS - 1);
                const int h = col >> 6, vv = col & 63;
                union { unsigned short u[4]; unsigned long long q; } x;
                #pragma unroll
                for (int j = 0; j < 4; ++j) x.u[j] = f2bf(v[j] + bb);
                *(unsigned long long*)&VWt[((size_t)(b * HH + h) * 64 + vv) * SS + s] = x.q;
            } else {
                unsigned short* C = z == 0 ? QWp : KWp;
                #pragma unroll
                for (int j = 0; j < 4; ++j)
                    C[(size_t)(rbase + j) * DM + col] = f2bf((v[j] + bb) * scale);
            }
        }
    }
}

// ---------------------------------------------------------------------------
// output projection GEMM: fp32 out = CC * Wot^T + bo
// ---------------------------------------------------------------------------
__global__ __launch_bounds__(256) void outproj_kernel(
    const unsigned short* __restrict__ A, const unsigned short* __restrict__ Bt,
    const float* __restrict__ bias, float* __restrict__ Cout) {
    __shared__ unsigned short As[128 * 64];
    __shared__ unsigned short Bs[128 * 64];
    const int tid = threadIdx.x;
    const int r0 = blockIdx.x * 128, n0 = blockIdx.y * 128;
    const int w = tid >> 6, lane = tid & 63, lr = lane & 15, lg = lane >> 4;
    const int wr = (w >> 1) * 64, wc = (w & 1) * 64;

    const f32x4 zf = {0.f, 0.f, 0.f, 0.f};
    f32x4 acc[4][4];
    #pragma unroll
    for (int mi = 0; mi < 4; ++mi)
        #pragma unroll
        for (int ni = 0; ni < 4; ++ni) acc[mi][ni] = zf;

    for (int k0 = 0; k0 < DM; k0 += 64) {
        #pragma unroll
        for (int i = 0; i < 4; ++i) {
            const int idx = tid + i * 256;
            const int row = idx >> 3, c8 = (idx & 7) * 8;
            gld16(&A[(size_t)(r0 + row) * DM + k0 + c8], &As[idx * 8]);
            gld16(&Bt[(size_t)(n0 + row) * DM + k0 + c8], &Bs[idx * 8]);
        }
        __syncthreads();
        #pragma unroll
        for (int kc = 0; kc < 2; ++kc) {
            short8 a[4], b[4];
            #pragma unroll
            for (int i = 0; i < 4; ++i) {
                a[i] = *(const short8*)&As[(wr + i * 16 + lr) * 64 + kc * 32 + lg * 8];
                b[i] = *(const short8*)&Bs[(wc + i * 16 + lr) * 64 + kc * 32 + lg * 8];
            }
            #pragma unroll
            for (int mi = 0; mi < 4; ++mi)
                #pragma unroll
                for (int ni = 0; ni < 4; ++ni)
                    acc[mi][ni] = MFMA16(a[mi], b[ni], acc[mi][ni]);
        }
        __syncthreads();
    }

    #pragma unroll
    for (int ni = 0; ni < 4; ++ni) {
        const int col = n0 + wc + ni * 16 + lr;
        const float bb = bias[col];
        #pragma unroll
        for (int mi = 0; mi < 4; ++mi) {
            const int rbase = r0 + wr + mi * 16 + lg * 4;
            const f32x4 v = acc[mi][ni];
            #pragma unroll
            for (int j = 0; j < 4; ++j)
                Cout[(size_t)(rbase + j) * DM + col] = v[j] + bb;
        }
    }
}

// ---------------------------------------------------------------------------
// MFMA flash attention, swapped-operand 32x32x16, KV-split x2.
// Grid (S/128, B*H, 2). Block: 128 q rows, 4 waves x 32; KV range = half of S.
// Scores arrive in exp2 domain (Q pre-scaled by log2e). No max subtraction.
// Writes raw partial O (bf16, q-major) + partial l (fp32); combine sums.
// K/V staged via global_load_lds with PRE-SWIZZLED global source chunk
// (c8 ^ (row&7)); FRAG reads apply the same XOR -> bank-balanced.
// ---------------------------------------------------------------------------
#define FRAG(buf, row, col) \
    (*(const short8*)&buf[(row) * 64 + ((col) ^ (((row) & 7) << 3))])

__global__ __launch_bounds__(256) void attn_kernel(
    const unsigned short* __restrict__ QW,   // [B, S, H*64] (exp2-scaled)
    const unsigned short* __restrict__ KW,   // [B, S, H*64]
    const unsigned short* __restrict__ VWt,  // [B*H, 64, S]
    unsigned short* __restrict__ Opart,      // [2][32][S][64] bf16 raw partial
    float* __restrict__ Lpart) {             // [2][32][S]
    __shared__ unsigned short Ks[64 * 64];   // [t_local][d], source-swizzled
    __shared__ unsigned short Vs[64 * 64];   // [v][t_local], source-swizzled
    const int tid = threadIdx.x;
    const int w = tid >> 6, lane = tid & 63;
    const int ql = lane & 31, hi = lane >> 5;
    const int bh = blockIdx.y, b = bh >> 4;
    const int h = bh & 15, z = blockIdx.z;
    const int row0 = blockIdx.x * 128;
    const int q = row0 + w * 32 + ql;

    short8 qf[4];
    const unsigned short* Qp = QW + ((size_t)b * SS + q) * DM + h * DK;
    #pragma unroll
    for (int kc = 0; kc < 4; ++kc)
        qf[kc] = *(const short8*)(Qp + kc * 16 + hi * 8);

    const unsigned short* Kp = KW + (size_t)b * SS * DM + h * DK;
    const unsigned short* Vt = VWt + (size_t)bh * 64 * SS;

    const f32x16 z16 = {0.f};
    f32x16 o0 = z16, o1 = z16;
    float lacc = 0.f;

    const int tbeg = z * (SS / 2), tend = tbeg + SS / 2;
    for (int t0 = tbeg; t0 < tend; t0 += 64) {
        #pragma unroll
        for (int r2 = 0; r2 < 2; ++r2) {
            const int idx = tid + r2 * 256;
            const int row = idx >> 3, c8 = idx & 7;
            const int cg = (c8 ^ (row & 7)) * 8;   // inverse-swizzled source
            gld16(&Kp[(size_t)(t0 + row) * DM + cg], &Ks[idx * 8]);
            gld16(&Vt[(size_t)row * SS + t0 + cg], &Vs[idx * 8]);
        }
        __syncthreads();

        // S[k][q] = mfma(K, Q): lane owns q=ql, k = 32kt + 8(r>>2) + 4hi + (r&3)
        f32x16 s0 = z16, s1 = z16;
        #pragma unroll
        for (int kc = 0; kc < 4; ++kc) {
            s0 = MFMA32(FRAG(Ks, ql, kc * 16 + hi * 8), qf[kc], s0);
            s1 = MFMA32(FRAG(Ks, 32 + ql, kc * 16 + hi * 8), qf[kc], s1);
        }

        // 2^s (exp2 domain), deferred l accumulation
        #pragma unroll
        for (int r = 0; r < 16; ++r) {
            const float e0 = EXP2(s0[r]);
            const float e1 = EXP2(s1[r]);
            s0[r] = e0; s1[r] = e1;
            lacc += e0 + e1;
        }

        // P -> bf16 B-fragments via cvt_pk + half-exchange
        short8 pa[4];
        #pragma unroll
        for (int ks = 0; ks < 4; ++ks) {
            const f32x16 sx = (ks < 2) ? s0 : s1;
            const int b0 = (ks & 1) * 8;
            unsigned x, x2, y, y2;
            asm("v_cvt_pk_bf16_f32 %0, %1, %2" : "=v"(x)  : "v"(sx[b0+0]), "v"(sx[b0+1]));
            asm("v_cvt_pk_bf16_f32 %0, %1, %2" : "=v"(x2) : "v"(sx[b0+2]), "v"(sx[b0+3]));
            asm("v_cvt_pk_bf16_f32 %0, %1, %2" : "=v"(y)  : "v"(sx[b0+4]), "v"(sx[b0+5]));
            asm("v_cvt_pk_bf16_f32 %0, %1, %2" : "=v"(y2) : "v"(sx[b0+6]), "v"(sx[b0+7]));
            const unsigned xx  = (unsigned)__shfl_xor((int)x, 32, 64);
            const unsigned yy  = (unsigned)__shfl_xor((int)y, 32, 64);
            const unsigned x2x = (unsigned)__shfl_xor((int)x2, 32, 64);
            const unsigned y2x = (unsigned)__shfl_xor((int)y2, 32, 64);
            union { unsigned u[4]; short8 s8; } pk;
            pk.u[0] = hi ? yy  : x;
            pk.u[1] = hi ? y2x : x2;
            pk.u[2] = hi ? y   : xx;
            pk.u[3] = hi ? y2  : x2x;
            pa[ks] = pk.s8;
        }

        // O^T[v][q] += V^T x P
        #pragma unroll
        for (int ks = 0; ks < 4; ++ks) {
            o0 = MFMA32(FRAG(Vs, ql, ks * 16 + hi * 8), pa[ks], o0);
            o1 = MFMA32(FRAG(Vs, 32 + ql, ks * 16 + hi * 8), pa[ks], o1);
        }
        __syncthreads();
    }

    // partial epilogue: raw O (bf16) + l (fp32)
    const float lt = lacc + __shfl_xor(lacc, 32, 64);
    unsigned short* Op = Opart + (((size_t)z * 32 + bh) * SS + q) * 64;
    #pragma unroll
    for (int vt = 0; vt < 2; ++vt) {
        const f32x16 ov = vt ? o1 : o0;
        #pragma unroll
        for (int m2 = 0; m2 < 4; ++m2) {
            union { unsigned short u[4]; unsigned long long q8; } pk;
            #pragma unroll
            for (int c = 0; c < 4; ++c) pk.u[c] = f2bf(ov[m2 * 4 + c]);
            *(unsigned long long*)(Op + vt * 32 + m2 * 8 + hi * 4) = pk.q8;
        }
    }
    if (hi == 0) Lpart[((size_t)z * 32 + bh) * SS + q] = lt;
}

// ---------------------------------------------------------------------------
// combine: CC[b][q][h*64+v] = (O0+O1) / (128*(l0+l1)), bf16
// ---------------------------------------------------------------------------
__global__ __launch_bounds__(256) void combine_kernel(
    const unsigned short* __restrict__ Opart, const float* __restrict__ Lpart,
    unsigned short* __restrict__ CC) {
    const int idx = blockIdx.x * 256 + threadIdx.x;
    const int v0 = (idx & 7) * 8, q = (idx >> 3) & (SS - 1), bh = idx >> 14;
    const size_t po = ((size_t)bh * SS + q) * 64 + v0;
    const size_t ps = (size_t)32 * SS * 64;
    union { uint4 v; unsigned short u[8]; } ua, ub, uo;
    ua.v = *(const uint4*)(Opart + po);
    ub.v = *(const uint4*)(Opart + ps + po);
    const float l = Lpart[(size_t)bh * SS + q] + Lpart[(size_t)32 * SS + bh * SS + q];
    const float inv = 1.0f / (128.0f * l);
    #pragma unroll
    for (int j = 0; j < 8; ++j)
        uo.u[j] = f2bf((bf2f(ua.u[j]) + bf2f(ub.u[j])) * inv);
    *(uint4*)&CC[((size_t)(bh >> 4) * SS + q) * DM + (bh & 15) * 64 + v0] = uo.v;
}

extern "C" void kernel_launch(void* const* d_in, const int* in_sizes, int n_in,
                              void* d_out, int out_size, void* d_ws, size_t ws_size,
                              hipStream_t stream) {
    const float* Q  = (const float*)d_in[0];
    const float* K  = (const float*)d_in[1];
    const float* V  = (const float*)d_in[2];
    const float* Wq = (const float*)d_in[3];
    const float* bq = (const float*)d_in[4];
    const float* Wk = (const float*)d_in[5];
    const float* bk = (const float*)d_in[6];
    const float* Wv = (const float*)d_in[7];
    const float* bv = (const float*)d_in[8];
    const float* Wo = (const float*)d_in[9];
    const float* bo = (const float*)d_in[10];
    float* out = (float*)d_out;

    // workspace (ushort units). Lifetimes:
    //   Qb,Kb,Vb:    cvt -> qkv_gemm         (dead after)
    //   Wqt..Wvt:    wtrans -> qkv_gemm      (dead after)
    //   QWp,KWp,VWt: qkv_gemm -> attn        (dead after)
    //   Opart = Kb..Vb (2*MK), Lpart = Wqt, CC = Qb  (attn -> combine -> outproj)
    unsigned short* ws = (unsigned short*)d_ws;
    const size_t MK = (size_t)BB * SS * DM;
    const size_t WK = (size_t)DM * DM;
    unsigned short* Qb  = ws;
    unsigned short* Kb  = Qb + MK;
    unsigned short* Vb  = Kb + MK;
    unsigned short* Wqt = Vb + MK;
    unsigned short* Wkt = Wqt + WK;
    unsigned short* Wvt = Wkt + WK;
    unsigned short* Wot = Wvt + WK;
    unsigned short* QWp = Wot + WK;
    unsigned short* KWp = QWp + MK;
    unsigned short* VWt = KWp + MK;
    unsigned short* Opart = Kb;          // 2*MK
    float*          Lpart = (float*)Wqt; // 512 KB
    unsigned short* CCp   = Qb;

    dim3 blk(256);
    const int M = BB * SS;

    hipLaunchKernelGGL(cvt3_kernel, dim3(MK / 2048, 3), blk, 0, stream,
                       Q, K, V, Qb, Kb, Vb);

    hipLaunchKernelGGL(wtrans_kernel, dim3(16, 1, 16), blk, 0, stream,
                       Wq, Wqt, DM, DK, DM * DK, DK * DM);
    hipLaunchKernelGGL(wtrans_kernel, dim3(16, 1, 16), blk, 0, stream,
                       Wk, Wkt, DM, DK, DM * DK, DK * DM);
    hipLaunchKernelGGL(wtrans_kernel, dim3(16, 1, 16), blk, 0, stream,
                       Wv, Wvt, DM, DK, DM * DK, DK * DM);
    hipLaunchKernelGGL(wtrans_kernel, dim3(16, 16, 1), blk, 0, stream,
                       Wo, Wot, DM, DM, 0, 0);

    hipLaunchKernelGGL(qkv_gemm_kernel, dim3(M / 128, 8, 3), blk, 0, stream,
                       Qb, Kb, Vb, Wqt, Wkt, Wvt, bq, bk, bv, QWp, KWp, VWt);

    hipLaunchKernelGGL(attn_kernel, dim3(SS / 128, BB * HH, 2), blk, 0, stream,
                       QWp, KWp, VWt, Opart, Lpart);

    hipLaunchKernelGGL(combine_kernel, dim3((32 * SS * 8) / 256), blk, 0, stream,
                       Opart, Lpart, CCp);

    hipLaunchKernelGGL(outproj_kernel, dim3(M / 128, 8), blk, 0, stream,
                       CCp, Wot, bo, out);
}

// Round 5
// 156.008 us; speedup vs baseline: 6.8683x; 1.0619x over previous
//
#include <hip/hip_runtime.h>

#define BB 2
#define SS 2048
#define DM 1024
#define HH 16
#define DK 64
#define LOG2E 1.44269504088896340736f

typedef __attribute__((ext_vector_type(8))) short short8;
typedef __attribute__((ext_vector_type(4))) float f32x4;
typedef __attribute__((ext_vector_type(16))) float f32x16;

#define MFMA16(a, b, c) __builtin_amdgcn_mfma_f32_16x16x32_bf16(a, b, c, 0, 0, 0)
#define MFMA32(a, b, c) __builtin_amdgcn_mfma_f32_32x32x16_bf16(a, b, c, 0, 0, 0)

#if __has_builtin(__builtin_amdgcn_exp2f)
#define EXP2(x) __builtin_amdgcn_exp2f(x)
#else
#define EXP2(x) __expf((x) * 0.6931471805599453f)
#endif

static __device__ __forceinline__ unsigned short f2bf(float f) {
    unsigned u = __builtin_bit_cast(unsigned, f);
    u += 0x7fffu + ((u >> 16) & 1u);   // RNE
    return (unsigned short)(u >> 16);
}
static __device__ __forceinline__ float bf2f(unsigned short u) {
    return __builtin_bit_cast(float, ((unsigned)u) << 16);
}

// async global->LDS, 16B per lane; LDS dest must be linear (base + lane*16)
static __device__ __forceinline__ void gld16(const void* g, void* l) {
    __builtin_amdgcn_global_load_lds(
        (const __attribute__((address_space(1))) unsigned int*)g,
        (__attribute__((address_space(3))) unsigned int*)l, 16, 0, 0);
}

// ---------------------------------------------------------------------------
// fp32 -> bf16 for Q,K,V in one launch (blockIdx.y selects matrix)
// ---------------------------------------------------------------------------
__global__ __launch_bounds__(256) void cvt3_kernel(
    const float* __restrict__ p0, const float* __restrict__ p1,
    const float* __restrict__ p2, unsigned short* __restrict__ o0,
    unsigned short* __restrict__ o1, unsigned short* __restrict__ o2) {
    const int m = blockIdx.y;
    const float* in = m == 0 ? p0 : (m == 1 ? p1 : p2);
    unsigned short* out = m == 0 ? o0 : (m == 1 ? o1 : o2);
    const int i = (blockIdx.x * 256 + threadIdx.x) * 8;
    float4 a = *(const float4*)(in + i);
    float4 b = *(const float4*)(in + i + 4);
    union { unsigned short u[8]; uint4 v; } x;
    x.u[0] = f2bf(a.x); x.u[1] = f2bf(a.y); x.u[2] = f2bf(a.z); x.u[3] = f2bf(a.w);
    x.u[4] = f2bf(b.x); x.u[5] = f2bf(b.y); x.u[6] = f2bf(b.z); x.u[7] = f2bf(b.w);
    *(uint4*)(out + i) = x.v;
}

// ---------------------------------------------------------------------------
// all 4 weight transposes in one launch. blockIdx.y = {Wq,Wk,Wv,Wo}.
// Wq/Wk/Wv: per-head [1024][64] -> [64][1024], 16 heads (blockIdx.x = h*16+rt)
// Wo:       [1024][1024] -> [1024][1024]^T     (blockIdx.x = ct*16+rt)
// ---------------------------------------------------------------------------
__global__ __launch_bounds__(256) void wtrans4_kernel(
    const float* __restrict__ Wq, const float* __restrict__ Wk,
    const float* __restrict__ Wv, const float* __restrict__ Wo,
    unsigned short* __restrict__ Wqt, unsigned short* __restrict__ Wkt,
    unsigned short* __restrict__ Wvt, unsigned short* __restrict__ Wot) {
    __shared__ float t[64][65];
    const int which = blockIdx.y;
    const float* in;
    unsigned short* out;
    int r0, c0, C;
    if (which < 3) {
        in = which == 0 ? Wq : (which == 1 ? Wk : Wv);
        out = which == 0 ? Wqt : (which == 1 ? Wkt : Wvt);
        const int h = blockIdx.x >> 4;
        r0 = (blockIdx.x & 15) * 64; c0 = 0; C = DK;
        in += (size_t)h * DM * DK;
        out += (size_t)h * DK * DM;
    } else {
        in = Wo; out = Wot;
        r0 = (blockIdx.x & 15) * 64; c0 = (blockIdx.x >> 4) * 64; C = DM;
    }
    const int lr = threadIdx.x & 63, gg = threadIdx.x >> 6;
    #pragma unroll
    for (int p = 0; p < 16; ++p) {
        const int r = p * 4 + gg;
        t[r][lr] = in[(size_t)(r0 + r) * C + c0 + lr];
    }
    __syncthreads();
    #pragma unroll
    for (int p = 0; p < 16; ++p) {
        const int c = p * 4 + gg;
        out[(size_t)(c0 + c) * DM + r0 + lr] = f2bf(t[lr][c]);
    }
}

// ---------------------------------------------------------------------------
// fused QKV projection GEMM: z = blockIdx.z selects {Q,K,V}.
// z==0: bf16 store scaled by log2(e); z==1: bf16; z==2: bf16 per-head transposed
// ---------------------------------------------------------------------------
__global__ __launch_bounds__(256) void qkv_gemm_kernel(
    const unsigned short* __restrict__ Qb, const unsigned short* __restrict__ Kb,
    const unsigned short* __restrict__ Vb,
    const unsigned short* __restrict__ Wqt, const unsigned short* __restrict__ Wkt,
    const unsigned short* __restrict__ Wvt,
    const float* __restrict__ bq, const float* __restrict__ bk,
    const float* __restrict__ bv,
    unsigned short* __restrict__ QWp, unsigned short* __restrict__ KWp,
    unsigned short* __restrict__ VWt) {
    __shared__ unsigned short As[128 * 64];
    __shared__ unsigned short Bs[128 * 64];
    const int z = blockIdx.z;
    const unsigned short* A  = z == 0 ? Qb : (z == 1 ? Kb : Vb);
    const unsigned short* Bt = z == 0 ? Wqt : (z == 1 ? Wkt : Wvt);
    const float* bias = z == 0 ? bq : (z == 1 ? bk : bv);
    const int tid = threadIdx.x;
    const int r0 = blockIdx.x * 128, n0 = blockIdx.y * 128;
    const int w = tid >> 6, lane = tid & 63, lr = lane & 15, lg = lane >> 4;
    const int wr = (w >> 1) * 64, wc = (w & 1) * 64;

    const f32x4 zf = {0.f, 0.f, 0.f, 0.f};
    f32x4 acc[4][4];
    #pragma unroll
    for (int mi = 0; mi < 4; ++mi)
        #pragma unroll
        for (int ni = 0; ni < 4; ++ni) acc[mi][ni] = zf;

    for (int k0 = 0; k0 < DM; k0 += 64) {
        #pragma unroll
        for (int i = 0; i < 4; ++i) {
            const int idx = tid + i * 256;
            const int row = idx >> 3, c8 = (idx & 7) * 8;
            gld16(&A[(size_t)(r0 + row) * DM + k0 + c8], &As[idx * 8]);
            gld16(&Bt[(size_t)(n0 + row) * DM + k0 + c8], &Bs[idx * 8]);
        }
        __syncthreads();
        #pragma unroll
        for (int kc = 0; kc < 2; ++kc) {
            short8 a[4], b[4];
            #pragma unroll
            for (int i = 0; i < 4; ++i) {
                a[i] = *(const short8*)&As[(wr + i * 16 + lr) * 64 + kc * 32 + lg * 8];
                b[i] = *(const short8*)&Bs[(wc + i * 16 + lr) * 64 + kc * 32 + lg * 8];
            }
            #pragma unroll
            for (int mi = 0; mi < 4; ++mi)
                #pragma unroll
                for (int ni = 0; ni < 4; ++ni)
                    acc[mi][ni] = MFMA16(a[mi], b[ni], acc[mi][ni]);
        }
        __syncthreads();
    }

    const float scale = (z == 0) ? LOG2E : 1.0f;
    #pragma unroll
    for (int ni = 0; ni < 4; ++ni) {
        const int col = n0 + wc + ni * 16 + lr;
        const float bb = bias[col];
        #pragma unroll
        for (int mi = 0; mi < 4; ++mi) {
            const int rbase = r0 + wr + mi * 16 + lg * 4;
            const f32x4 v = acc[mi][ni];
            if (z == 2) {
                const int b = rbase >> 11, s = rbase & (SS - 1);
                const int h = col >> 6, vv = col & 63;
                union { unsigned short u[4]; unsigned long long q; } x;
                #pragma unroll
                for (int j = 0; j < 4; ++j) x.u[j] = f2bf(v[j] + bb);
                *(unsigned long long*)&VWt[((size_t)(b * HH + h) * 64 + vv) * SS + s] = x.q;
            } else {
                unsigned short* C = z == 0 ? QWp : KWp;
                #pragma unroll
                for (int j = 0; j < 4; ++j)
                    C[(size_t)(rbase + j) * DM + col] = f2bf((v[j] + bb) * scale);
            }
        }
    }
}

// ---------------------------------------------------------------------------
// output projection GEMM: fp32 out = CC * Wot^T + bo
// ---------------------------------------------------------------------------
__global__ __launch_bounds__(256) void outproj_kernel(
    const unsigned short* __restrict__ A, const unsigned short* __restrict__ Bt,
    const float* __restrict__ bias, float* __restrict__ Cout) {
    __shared__ unsigned short As[128 * 64];
    __shared__ unsigned short Bs[128 * 64];
    const int tid = threadIdx.x;
    const int r0 = blockIdx.x * 128, n0 = blockIdx.y * 128;
    const int w = tid >> 6, lane = tid & 63, lr = lane & 15, lg = lane >> 4;
    const int wr = (w >> 1) * 64, wc = (w & 1) * 64;

    const f32x4 zf = {0.f, 0.f, 0.f, 0.f};
    f32x4 acc[4][4];
    #pragma unroll
    for (int mi = 0; mi < 4; ++mi)
        #pragma unroll
        for (int ni = 0; ni < 4; ++ni) acc[mi][ni] = zf;

    for (int k0 = 0; k0 < DM; k0 += 64) {
        #pragma unroll
        for (int i = 0; i < 4; ++i) {
            const int idx = tid + i * 256;
            const int row = idx >> 3, c8 = (idx & 7) * 8;
            gld16(&A[(size_t)(r0 + row) * DM + k0 + c8], &As[idx * 8]);
            gld16(&Bt[(size_t)(n0 + row) * DM + k0 + c8], &Bs[idx * 8]);
        }
        __syncthreads();
        #pragma unroll
        for (int kc = 0; kc < 2; ++kc) {
            short8 a[4], b[4];
            #pragma unroll
            for (int i = 0; i < 4; ++i) {
                a[i] = *(const short8*)&As[(wr + i * 16 + lr) * 64 + kc * 32 + lg * 8];
                b[i] = *(const short8*)&Bs[(wc + i * 16 + lr) * 64 + kc * 32 + lg * 8];
            }
            #pragma unroll
            for (int mi = 0; mi < 4; ++mi)
                #pragma unroll
                for (int ni = 0; ni < 4; ++ni)
                    acc[mi][ni] = MFMA16(a[mi], b[ni], acc[mi][ni]);
        }
        __syncthreads();
    }

    #pragma unroll
    for (int ni = 0; ni < 4; ++ni) {
        const int col = n0 + wc + ni * 16 + lr;
        const float bb = bias[col];
        #pragma unroll
        for (int mi = 0; mi < 4; ++mi) {
            const int rbase = r0 + wr + mi * 16 + lg * 4;
            const f32x4 v = acc[mi][ni];
            #pragma unroll
            for (int j = 0; j < 4; ++j)
                Cout[(size_t)(rbase + j) * DM + col] = v[j] + bb;
        }
    }
}

// ---------------------------------------------------------------------------
// MFMA flash attention, swapped-operand 32x32x16, KV-split x2,
// double-buffered K/V (2-phase: issue next tile's global_load_lds BEFORE
// computing current; one syncthreads (=vmcnt(0)+barrier) per tile).
// P-pack via v_permlane32_swap_b32 (no LDS shuffles, no selects).
// ---------------------------------------------------------------------------
#define FRAG(buf, row, col) \
    (*(const short8*)&buf[(row) * 64 + ((col) ^ (((row) & 7) << 3))])

__global__ __launch_bounds__(256) void attn_kernel(
    const unsigned short* __restrict__ QW,   // [B, S, H*64] (exp2-scaled)
    const unsigned short* __restrict__ KW,   // [B, S, H*64]
    const unsigned short* __restrict__ VWt,  // [B*H, 64, S]
    unsigned short* __restrict__ Opart,      // [2][32][S][64] bf16 raw partial
    float* __restrict__ Lpart) {             // [2][32][S]
    __shared__ unsigned short Ks[2][64 * 64];
    __shared__ unsigned short Vs[2][64 * 64];
    const int tid = threadIdx.x;
    const int w = tid >> 6, lane = tid & 63;
    const int ql = lane & 31, hi = lane >> 5;
    const int bh = blockIdx.y, b = bh >> 4;
    const int h = bh & 15, z = blockIdx.z;
    const int row0 = blockIdx.x * 128;
    const int q = row0 + w * 32 + ql;

    short8 qf[4];
    const unsigned short* Qp = QW + ((size_t)b * SS + q) * DM + h * DK;
    #pragma unroll
    for (int kc = 0; kc < 4; ++kc)
        qf[kc] = *(const short8*)(Qp + kc * 16 + hi * 8);

    const unsigned short* Kp = KW + (size_t)b * SS * DM + h * DK;
    const unsigned short* Vt = VWt + (size_t)bh * 64 * SS;

    // staging addresses for this thread (8 x 16B per tile: 2 K + 2 V chunks x2)
    const int sidx0 = tid, sidx1 = tid + 256;
    const int srow0 = sidx0 >> 3, sc0 = ((sidx0 & 7) ^ (srow0 & 7)) * 8;
    const int srow1 = sidx1 >> 3, sc1 = ((sidx1 & 7) ^ (srow1 & 7)) * 8;

#define STAGE(t0, pp)                                                        \
    do {                                                                     \
        gld16(&Kp[(size_t)((t0) + srow0) * DM + sc0], &Ks[pp][sidx0 * 8]);   \
        gld16(&Vt[(size_t)srow0 * SS + (t0) + sc0], &Vs[pp][sidx0 * 8]);     \
        gld16(&Kp[(size_t)((t0) + srow1) * DM + sc1], &Ks[pp][sidx1 * 8]);   \
        gld16(&Vt[(size_t)srow1 * SS + (t0) + sc1], &Vs[pp][sidx1 * 8]);     \
    } while (0)

    const f32x16 z16 = {0.f};
    f32x16 o0 = z16, o1 = z16;
    float lacc = 0.f;

    const int tbeg = z * (SS / 2), tend = tbeg + SS / 2;
    STAGE(tbeg, 0);
    __syncthreads();

    int p = 0;
    for (int t0 = tbeg; t0 < tend; t0 += 64) {
        if (t0 + 64 < tend) STAGE(t0 + 64, p ^ 1);   // prefetch next tile

        // S[k][q] = mfma(K, Q): lane owns q=ql, k = 32kt + 8(r>>2) + 4hi + (r&3)
        f32x16 s0 = z16, s1 = z16;
        __builtin_amdgcn_s_setprio(1);
        #pragma unroll
        for (int kc = 0; kc < 4; ++kc) {
            s0 = MFMA32(FRAG(Ks[p], ql, kc * 16 + hi * 8), qf[kc], s0);
            s1 = MFMA32(FRAG(Ks[p], 32 + ql, kc * 16 + hi * 8), qf[kc], s1);
        }
        __builtin_amdgcn_s_setprio(0);

        // 2^s (exp2 domain), deferred l accumulation
        #pragma unroll
        for (int r = 0; r < 16; ++r) {
            const float e0 = EXP2(s0[r]);
            const float e1 = EXP2(s1[r]);
            s0[r] = e0; s1[r] = e1;
            lacc += e0 + e1;
        }

        // P -> bf16 B-fragments: cvt_pk pairs + permlane32_swap half-exchange.
        // swap(x,y): x' = [x_lo | y_lo->hi], y' = [x_hi->lo | y_hi]
        short8 pa[4];
        #pragma unroll
        for (int ks = 0; ks < 4; ++ks) {
            const f32x16 sx = (ks < 2) ? s0 : s1;
            const int b0 = (ks & 1) * 8;
            unsigned x, x2, y, y2;
            asm("v_cvt_pk_bf16_f32 %0, %1, %2" : "=v"(x)  : "v"(sx[b0+0]), "v"(sx[b0+1]));
            asm("v_cvt_pk_bf16_f32 %0, %1, %2" : "=v"(x2) : "v"(sx[b0+2]), "v"(sx[b0+3]));
            asm("v_cvt_pk_bf16_f32 %0, %1, %2" : "=v"(y)  : "v"(sx[b0+4]), "v"(sx[b0+5]));
            asm("v_cvt_pk_bf16_f32 %0, %1, %2" : "=v"(y2) : "v"(sx[b0+6]), "v"(sx[b0+7]));
            asm("v_permlane32_swap_b32 %0, %1" : "+v"(x),  "+v"(y));
            asm("v_permlane32_swap_b32 %0, %1" : "+v"(x2), "+v"(y2));
            union { unsigned u[4]; short8 s8; } pk;
            pk.u[0] = x;    // k pair 16ks+0,1   (own lo / partner lo)
            pk.u[1] = x2;   // +2,3
            pk.u[2] = y;    // +4,5   (partner hi / own hi)
            pk.u[3] = y2;   // +6,7
            pa[ks] = pk.s8;
        }

        // O^T[v][q] += V^T x P
        __builtin_amdgcn_s_setprio(1);
        #pragma unroll
        for (int ks = 0; ks < 4; ++ks) {
            o0 = MFMA32(FRAG(Vs[p], ql, ks * 16 + hi * 8), pa[ks], o0);
            o1 = MFMA32(FRAG(Vs[p], 32 + ql, ks * 16 + hi * 8), pa[ks], o1);
        }
        __builtin_amdgcn_s_setprio(0);

        __syncthreads();   // drains prefetch (vmcnt 0) + protects buffers
        p ^= 1;
    }
#undef STAGE

    // partial epilogue: raw O (bf16) + l (fp32)
    const float lt = lacc + __shfl_xor(lacc, 32, 64);
    unsigned short* Op = Opart + (((size_t)z * 32 + bh) * SS + q) * 64;
    #pragma unroll
    for (int vt = 0; vt < 2; ++vt) {
        const f32x16 ov = vt ? o1 : o0;
        #pragma unroll
        for (int m2 = 0; m2 < 4; ++m2) {
            union { unsigned short u[4]; unsigned long long q8; } pk;
            #pragma unroll
            for (int c = 0; c < 4; ++c) pk.u[c] = f2bf(ov[m2 * 4 + c]);
            *(unsigned long long*)(Op + vt * 32 + m2 * 8 + hi * 4) = pk.q8;
        }
    }
    if (hi == 0) Lpart[((size_t)z * 32 + bh) * SS + q] = lt;
}

// ---------------------------------------------------------------------------
// combine: CC[b][q][h*64+v] = (O0+O1) / (128*(l0+l1)), bf16
// ---------------------------------------------------------------------------
__global__ __launch_bounds__(256) void combine_kernel(
    const unsigned short* __restrict__ Opart, const float* __restrict__ Lpart,
    unsigned short* __restrict__ CC) {
    const int idx = blockIdx.x * 256 + threadIdx.x;
    const int v0 = (idx & 7) * 8, q = (idx >> 3) & (SS - 1), bh = idx >> 14;
    const size_t po = ((size_t)bh * SS + q) * 64 + v0;
    const size_t ps = (size_t)32 * SS * 64;
    union { uint4 v; unsigned short u[8]; } ua, ub, uo;
    ua.v = *(const uint4*)(Opart + po);
    ub.v = *(const uint4*)(Opart + ps + po);
    const float l = Lpart[(size_t)bh * SS + q] + Lpart[(size_t)32 * SS + bh * SS + q];
    const float inv = 1.0f / (128.0f * l);
    #pragma unroll
    for (int j = 0; j < 8; ++j)
        uo.u[j] = f2bf((bf2f(ua.u[j]) + bf2f(ub.u[j])) * inv);
    *(uint4*)&CC[((size_t)(bh >> 4) * SS + q) * DM + (bh & 15) * 64 + v0] = uo.v;
}

extern "C" void kernel_launch(void* const* d_in, const int* in_sizes, int n_in,
                              void* d_out, int out_size, void* d_ws, size_t ws_size,
                              hipStream_t stream) {
    const float* Q  = (const float*)d_in[0];
    const float* K  = (const float*)d_in[1];
    const float* V  = (const float*)d_in[2];
    const float* Wq = (const float*)d_in[3];
    const float* bq = (const float*)d_in[4];
    const float* Wk = (const float*)d_in[5];
    const float* bk = (const float*)d_in[6];
    const float* Wv = (const float*)d_in[7];
    const float* bv = (const float*)d_in[8];
    const float* Wo = (const float*)d_in[9];
    const float* bo = (const float*)d_in[10];
    float* out = (float*)d_out;

    unsigned short* ws = (unsigned short*)d_ws;
    const size_t MK = (size_t)BB * SS * DM;
    const size_t WK = (size_t)DM * DM;
    unsigned short* Qb  = ws;
    unsigned short* Kb  = Qb + MK;
    unsigned short* Vb  = Kb + MK;
    unsigned short* Wqt = Vb + MK;
    unsigned short* Wkt = Wqt + WK;
    unsigned short* Wvt = Wkt + WK;
    unsigned short* Wot = Wvt + WK;
    unsigned short* QWp = Wot + WK;
    unsigned short* KWp = QWp + MK;
    unsigned short* VWt = KWp + MK;
    unsigned short* Opart = Kb;          // 2*MK (Kb,Vb dead after qkv_gemm)
    float*          Lpart = (float*)Wqt; // 512 KB (dead after qkv_gemm)
    unsigned short* CCp   = Qb;          // dead after qkv_gemm

    dim3 blk(256);
    const int M = BB * SS;

    hipLaunchKernelGGL(cvt3_kernel, dim3(MK / 2048, 3), blk, 0, stream,
                       Q, K, V, Qb, Kb, Vb);

    hipLaunchKernelGGL(wtrans4_kernel, dim3(256, 4), blk, 0, stream,
                       Wq, Wk, Wv, Wo, Wqt, Wkt, Wvt, Wot);

    hipLaunchKernelGGL(qkv_gemm_kernel, dim3(M / 128, 8, 3), blk, 0, stream,
                       Qb, Kb, Vb, Wqt, Wkt, Wvt, bq, bk, bv, QWp, KWp, VWt);

    hipLaunchKernelGGL(attn_kernel, dim3(SS / 128, BB * HH, 2), blk, 0, stream,
                       QWp, KWp, VWt, Opart, Lpart);

    hipLaunchKernelGGL(combine_kernel, dim3((32 * SS * 8) / 256), blk, 0, stream,
                       Opart, Lpart, CCp);

    hipLaunchKernelGGL(outproj_kernel, dim3(M / 128, 8), blk, 0, stream,
                       CCp, Wot, bo, out);
}